// Round 2
// baseline (136.502 us; speedup 1.0000x reference)
//
#include <hip/hip_runtime.h>
#include <math.h>

#define S_ 2048
#define NH 8
#define LP 72         // bf16 LDS row pitch: 144 B = 9*16 B -> b128-aligned
#define RP 328        // R_lds pitch (bf16): 656 B rows, 16B-aligned, banks spread

typedef __attribute__((ext_vector_type(8))) short short8;   // 8 x bf16 (4 VGPRs)
typedef __attribute__((ext_vector_type(4))) float f32x4;    // MFMA accumulator
typedef unsigned short ushort_t;

__device__ __forceinline__ short bf16r(float x) {   // RNE float->bf16
    union { float f; unsigned u; } v; v.f = x;
    unsigned r = v.u + 0x7fffu + ((v.u >> 16) & 1u);
    return (short)(r >> 16);
}
__device__ __forceinline__ float b2f(ushort_t h) {  // bf16->float
    union { float f; unsigned u; } v; v.u = ((unsigned)h) << 16; return v.f;
}

// ---------------------------------------------------------------------------
// Kernel 0: prep.  z<4: WT[n][k] = bf16(W[k][n]) (LDS-tiled 64x64).
// z==4: pos table bf16; rows 257..383 zero.  z==5: xb16 = bf16(x).
// z==6: xpart[sub][c] = column partial sums of x (64 rows each) for vmean.
// ---------------------------------------------------------------------------
__global__ __launch_bounds__(256) void prep_kernel(
    const float* __restrict__ x,
    const float* __restrict__ Wq, const float* __restrict__ Wk,
    const float* __restrict__ Wv, const float* __restrict__ Wkr,
    ushort_t* __restrict__ WTq, ushort_t* __restrict__ WTk,
    ushort_t* __restrict__ WTv, ushort_t* __restrict__ WTkr,
    ushort_t* __restrict__ pos, ushort_t* __restrict__ xb16,
    float* __restrict__ xpart)
{
    const int widx = blockIdx.z;
    const int t = threadIdx.x;
    if (widx == 4) {
        const int base = blockIdx.y * 8 + blockIdx.x;    // 0..63
        const float C = -0.051905126482615036f;          // -log2(10000)/256
        const int f = t;
#pragma unroll
        for (int rep = 0; rep < 6; ++rep) {
            const int r = base + rep * 64;               // 0..383
            unsigned pk = 0;
            if (r <= 256) {
                float ang = (float)r * exp2f(C * (float)f);
                unsigned s = (unsigned)(ushort_t)bf16r(sinf(ang));
                unsigned c = (unsigned)(ushort_t)bf16r(cosf(ang));
                pk = s | (c << 16);
            }
            ((unsigned*)pos)[(size_t)r * 256 + f] = pk;
        }
        return;
    }
    if (widx == 5) {
        const int sub = blockIdx.y * 8 + blockIdx.x;     // 0..63
        const size_t base = (size_t)sub * 32768;
#pragma unroll
        for (int it = 0; it < 8; ++it) {
            const size_t idx = base + (size_t)it * 4096 + (size_t)t * 16;
            const float* src = &x[idx];
            ushort_t t16[16];
#pragma unroll
            for (int u = 0; u < 16; ++u) t16[u] = (ushort_t)bf16r(src[u]);
            *(short8*)&xb16[idx]     = *(short8*)&t16[0];
            *(short8*)&xb16[idx + 8] = *(short8*)&t16[8];
        }
        return;
    }
    if (widx == 6) {
        // column partial sums over 64-row stripes, for vmean matvec in qkv
        const int sub = blockIdx.y * 8 + blockIdx.x;     // 0..63
        const int b = sub >> 5, rb = sub & 31;
        const float* src = &x[((size_t)b * 2048 + (size_t)rb * 64) * 512];
        float s0 = 0.f, s1 = 0.f;
        for (int r = 0; r < 64; ++r) {
            s0 += src[(size_t)r * 512 + t];
            s1 += src[(size_t)r * 512 + t + 256];
        }
        xpart[(size_t)sub * 512 + t]       = s0;
        xpart[(size_t)sub * 512 + t + 256] = s1;
        return;
    }
    const float* W = (widx == 0) ? Wq : (widx == 1) ? Wk : (widx == 2) ? Wv : Wkr;
    ushort_t* WT   = (widx == 0) ? WTq : (widx == 1) ? WTk : (widx == 2) ? WTv : WTkr;
    const int k0 = blockIdx.x * 64, n0 = blockIdx.y * 64;
    __shared__ __align__(16) ushort_t T[64][72];
    const int srow = t >> 2, sc0 = (t & 3) * 16;
    const float* src = &W[(size_t)(k0 + srow) * 512 + n0 + sc0];
#pragma unroll
    for (int u = 0; u < 16; ++u) T[sc0 + u][srow] = (ushort_t)bf16r(src[u]);
    __syncthreads();
    ushort_t* dst = &WT[(size_t)(n0 + srow) * 512 + k0 + sc0];
    *(short8*)dst       = *(const short8*)&T[srow][sc0];
    *(short8*)(dst + 8) = *(const short8*)&T[srow][sc0 + 8];
}

// ---------------------------------------------------------------------------
// Kernel 1: fused QKV (+krel +vmean) GEMM via bf16 MFMA.  Grid (32, 26).
// xlen-aware: q tiles with s0 >= xlen+256 are never read; k tiles with
// s0 >= xlen+63 are never staged by attn.  by==25: vmean matvec from xpart.
// ---------------------------------------------------------------------------
__global__ __launch_bounds__(256) void qkv_gemm(
    const ushort_t* __restrict__ xb16,
    const ushort_t* __restrict__ WTq, const ushort_t* __restrict__ WTk,
    const ushort_t* __restrict__ WTv,
    const ushort_t* __restrict__ pos, const ushort_t* __restrict__ WTkr,
    const float* __restrict__ b_con, const float* __restrict__ b_rel,
    const float* __restrict__ bv, const int* __restrict__ xlen_p,
    const float* __restrict__ xpart,
    ushort_t* __restrict__ qcon, ushort_t* __restrict__ qrel,
    ushort_t* __restrict__ kout, ushort_t* __restrict__ vT,
    ushort_t* __restrict__ krel, float* __restrict__ vmean)
{
    const int widx = blockIdx.y >> 3;
    const int tid = threadIdx.x, lane = tid & 63, w = tid >> 6;
    const int quad = lane >> 4, l16 = lane & 15;

    __shared__ __align__(16) ushort_t A_lds[128][40];
    __shared__ __align__(16) ushort_t B_lds[64][40];

    f32x4 acc[2][4];
#pragma unroll
    for (int mt = 0; mt < 2; ++mt)
#pragma unroll
        for (int nt = 0; nt < 4; ++nt) acc[mt][nt] = (f32x4){0.f, 0.f, 0.f, 0.f};

    const int arow = tid >> 1, ak0 = (tid & 1) * 16;
    const int brow = tid >> 2, bk0 = (tid & 3) * 8;

    if (widx < 2) {
        const int m0 = blockIdx.x * 128;
        // ---- xlen elision: rows are (b, s) = (m0>>11, m0&2047) ----
        {
            const int xl = xlen_p[m0 >> 11];
            const int s0 = m0 & 2047;
            if (widx == 0) { if (s0 >= xl + 256) return; }   // q rows dead
            else           { if (s0 >= xl + 63)  return; }   // k rows never staged
        }
        const int n0 = (blockIdx.y & 7) * 64;
        const ushort_t* WT = (widx == 0) ? WTq : WTk;
        const ushort_t* xrow = &xb16[(size_t)(m0 + arow) * 512 + ak0];
        const ushort_t* wrow = &WT[(size_t)(n0 + brow) * 512 + bk0];

        short8 pa0 = *(const short8*)xrow;
        short8 pa1 = *(const short8*)(xrow + 8);
        short8 pb  = *(const short8*)wrow;

#pragma unroll 1
        for (int k0 = 0; k0 < 512; k0 += 32) {
            __syncthreads();   // prev iter's MFMA LDS reads done
            *(short8*)&A_lds[arow][ak0]     = pa0;
            *(short8*)&A_lds[arow][ak0 + 8] = pa1;
            *(short8*)&B_lds[brow][bk0]     = pb;
            if (k0 < 480) {
                pa0 = *(const short8*)(xrow + k0 + 32);
                pa1 = *(const short8*)(xrow + k0 + 40);
                pb  = *(const short8*)(wrow + k0 + 32);
            }
            __syncthreads();
            short8 a0 = *(const short8*)&A_lds[w * 32 + l16][quad * 8];
            short8 a1 = *(const short8*)&A_lds[w * 32 + 16 + l16][quad * 8];
#pragma unroll
            for (int nt = 0; nt < 4; ++nt) {
                short8 bb = *(const short8*)&B_lds[nt * 16 + l16][quad * 8];
                acc[0][nt] = __builtin_amdgcn_mfma_f32_16x16x32_bf16(a0, bb, acc[0][nt], 0, 0, 0);
                acc[1][nt] = __builtin_amdgcn_mfma_f32_16x16x32_bf16(a1, bb, acc[1][nt], 0, 0, 0);
            }
        }

#pragma unroll
        for (int nt = 0; nt < 4; ++nt) {
            const int col = n0 + nt * 16 + l16;
            float bc = 0.f, br = 0.f;
            if (widx == 0) { bc = b_con[col]; br = b_rel[col]; }
#pragma unroll
            for (int mt = 0; mt < 2; ++mt) {
#pragma unroll
                for (int reg = 0; reg < 4; ++reg) {
                    const size_t m = (size_t)(m0 + w * 32 + mt * 16 + quad * 4 + reg);
                    const float val = acc[mt][nt][reg];
                    if (widx == 0) {
                        qcon[m * 512 + col] = (ushort_t)bf16r((val + bc) * 0.125f);
                        qrel[m * 512 + col] = (ushort_t)bf16r((val + br) * 0.125f);
                    } else {
                        kout[m * 512 + col] = (ushort_t)bf16r(val);
                    }
                }
            }
        }
    } else if (widx == 2) {
        // ---- V transposed mode: vT[d][j] = WTv[d] . x[j] + bv ----
        const int vb = (blockIdx.y & 7) * 32 + blockIdx.x;   // 0..255
        const int m0d = (vb & 3) * 128;                      // d tile
        const int n0j = (vb >> 2) * 64;                      // seq tile
        const ushort_t* wrow = &WTv[(size_t)(m0d + arow) * 512 + ak0];
        const ushort_t* xrow = &xb16[(size_t)(n0j + brow) * 512 + bk0];

        short8 pa0 = *(const short8*)wrow;
        short8 pa1 = *(const short8*)(wrow + 8);
        short8 pb  = *(const short8*)xrow;

#pragma unroll 1
        for (int k0 = 0; k0 < 512; k0 += 32) {
            __syncthreads();
            *(short8*)&A_lds[arow][ak0]     = pa0;
            *(short8*)&A_lds[arow][ak0 + 8] = pa1;
            *(short8*)&B_lds[brow][bk0]     = pb;
            if (k0 < 480) {
                pa0 = *(const short8*)(wrow + k0 + 32);
                pa1 = *(const short8*)(wrow + k0 + 40);
                pb  = *(const short8*)(xrow + k0 + 32);
            }
            __syncthreads();
            short8 a0 = *(const short8*)&A_lds[w * 32 + l16][quad * 8];
            short8 a1 = *(const short8*)&A_lds[w * 32 + 16 + l16][quad * 8];
#pragma unroll
            for (int nt = 0; nt < 4; ++nt) {
                short8 bb = *(const short8*)&B_lds[nt * 16 + l16][quad * 8];
                acc[0][nt] = __builtin_amdgcn_mfma_f32_16x16x32_bf16(a0, bb, acc[0][nt], 0, 0, 0);
                acc[1][nt] = __builtin_amdgcn_mfma_f32_16x16x32_bf16(a1, bb, acc[1][nt], 0, 0, 0);
            }
        }

        const int b = n0j >> 11;
#pragma unroll
        for (int mt = 0; mt < 2; ++mt) {
#pragma unroll
            for (int reg = 0; reg < 4; ++reg) {
                const int d = m0d + w * 32 + mt * 16 + quad * 4 + reg;  // 0..511
                const int n = d >> 6, dd = d & 63;
                const float bvv = bv[d];
#pragma unroll
                for (int nt = 0; nt < 4; ++nt) {
                    const int s = (n0j + nt * 16 + l16) & 2047;
                    vT[((size_t)((b * NH + n) * 64 + dd)) * 2048 + s] =
                        (ushort_t)bf16r(acc[mt][nt][reg] + bvv);
                }
            }
        }
    } else {
        if (blockIdx.y == 25) {
            // ---- vmean: vmean[b][d] = mean_x[b] . WTv[d] + bv[d] ----
            if (blockIdx.x >= 8) return;
            float* xm = (float*)A_lds;                       // [2][512] fp32
            for (int idx = tid; idx < 1024; idx += 256) {
                const int bb = idx >> 9, k = idx & 511;
                float s = 0.f;
                for (int p = 0; p < 32; ++p)
                    s += xpart[(size_t)(bb * 32 + p) * 512 + k];
                xm[bb * 512 + k] = s * (1.0f / 2048.0f);
            }
            __syncthreads();
            if (tid < 64) {
                const int d = blockIdx.x * 64 + tid;
                const ushort_t* wrow = &WTv[(size_t)d * 512];
                float a0 = 0.f, a1 = 0.f;
                for (int k = 0; k < 512; k += 8) {
                    short8 wv = *(const short8*)(wrow + k);
#pragma unroll
                    for (int u = 0; u < 8; ++u) {
                        const float wf = b2f((ushort_t)wv[u]);
                        a0 += xm[k + u] * wf;
                        a1 += xm[512 + k + u] * wf;
                    }
                }
                const float bvd = bv[d];
                vmean[d]       = a0 + bvd;
                vmean[512 + d] = a1 + bvd;
            }
            return;
        }
        // ---- krel mode (by == 24): krel = pos @ Wkr ----
        if (blockIdx.x >= 24) return;
        const int m0 = (blockIdx.x >> 3) * 128;              // 0..255
        const int n0 = (blockIdx.x & 7) * 64;
        const ushort_t* prow = &pos[(size_t)(m0 + arow) * 512 + ak0];
        const ushort_t* wrow = &WTkr[(size_t)(n0 + brow) * 512 + bk0];

        short8 pa0 = *(const short8*)prow;
        short8 pa1 = *(const short8*)(prow + 8);
        short8 pb  = *(const short8*)wrow;

#pragma unroll 1
        for (int k0 = 0; k0 < 512; k0 += 32) {
            __syncthreads();
            *(short8*)&A_lds[arow][ak0]     = pa0;
            *(short8*)&A_lds[arow][ak0 + 8] = pa1;
            *(short8*)&B_lds[brow][bk0]     = pb;
            if (k0 < 480) {
                pa0 = *(const short8*)(prow + k0 + 32);
                pa1 = *(const short8*)(prow + k0 + 40);
                pb  = *(const short8*)(wrow + k0 + 32);
            }
            __syncthreads();
            short8 a0 = *(const short8*)&A_lds[w * 32 + l16][quad * 8];
            short8 a1 = *(const short8*)&A_lds[w * 32 + 16 + l16][quad * 8];
#pragma unroll
            for (int nt = 0; nt < 4; ++nt) {
                short8 bb = *(const short8*)&B_lds[nt * 16 + l16][quad * 8];
                acc[0][nt] = __builtin_amdgcn_mfma_f32_16x16x32_bf16(a0, bb, acc[0][nt], 0, 0, 0);
                acc[1][nt] = __builtin_amdgcn_mfma_f32_16x16x32_bf16(a1, bb, acc[1][nt], 0, 0, 0);
            }
        }

#pragma unroll
        for (int nt = 0; nt < 4; ++nt) {
            const int col = n0 + nt * 16 + l16;
#pragma unroll
            for (int mt = 0; mt < 2; ++mt)
#pragma unroll
                for (int reg = 0; reg < 4; ++reg) {
                    const size_t m = (size_t)(m0 + w * 32 + mt * 16 + quad * 4 + reg);
                    krel[m * 512 + col] = (ushort_t)bf16r(acc[mt][nt][reg]);
                }
        }
    }
}

// ---------------------------------------------------------------------------
// Kernel 5: banded attention, now with FUSED rel-energy (rel_gemm removed).
// Per block: RG[row][r] = qrel[i0+row].krel[r] via MFMA (B frags gathered
// from L2-resident krel), scattered into R_lds[row][row+256-r].  exp reads
// R_lds[row][64c+jcol] and overwrites the slot with p (in-place overlay, no
// separate p_lds).  Q held in registers.  LDS 38.9 KB -> 4 blocks/CU.
// ---------------------------------------------------------------------------
__global__ __launch_bounds__(128) void attn_kernel(
    const ushort_t* __restrict__ qcon, const ushort_t* __restrict__ qrel,
    const ushort_t* __restrict__ kbuf, const ushort_t* __restrict__ vT,
    const ushort_t* __restrict__ krel, const float* __restrict__ vmean,
    const int* __restrict__ xlen_p, float* __restrict__ out)
{
    const int bx = blockIdx.x;
    const int tile = ((bx & 7) << 3) | (bx >> 3);   // XCD swizzle
    const int n = blockIdx.y, b = blockIdx.z;
    const int i0 = tile * 32;
    const int tid = threadIdx.x, lane = tid & 63, w = tid >> 6;
    const int quad = lane >> 4, l16 = lane & 15;
    const int xlen = xlen_p[b];

    // ---- dead-tile fast path: every row fully masked -> uniform softmax ----
    if (i0 >= xlen + 256) {
        const int row = tid >> 2, c0f = (tid & 3) * 16;
        const float* vm = &vmean[(size_t)b * 512 + n * 64 + c0f];
        float* dst = &out[((size_t)b * S_ + i0 + row) * 512 + n * 64 + c0f];
#pragma unroll
        for (int u = 0; u < 16; u += 4)
            *(float4*)&dst[u] = *(const float4*)&vm[u];
        return;
    }
    int nchunk = (xlen - i0 + 256 + 63) >> 6;
    if (nchunk > 5) nchunk = 5;
    const int c0 = (i0 < 256) ? ((256 - i0) >> 6) : 0;   // chunks entirely j<0

    __shared__ __align__(16) ushort_t k_lds[64][LP];
    __shared__ __align__(16) ushort_t vT_lds[64][LP];
    __shared__ __align__(16) ushort_t R_lds[32][RP];

    // ---- Q-con fragments held in registers (own-wave rows only) ----
    const ushort_t* qc = &qcon[((size_t)b * S_ + i0 + w * 16 + l16) * 512 + n * 64 + quad * 8];
    const short8 aq0 = *(const short8*)qc;
    const short8 aq1 = *(const short8*)(qc + 32);

    // ---- RG phase: R_lds[row][row+256-r] = qrel[i0+row] . krel[r] ----
    {
        const ushort_t* qr = &qrel[((size_t)b * S_ + i0 + w * 16 + l16) * 512 + n * 64 + quad * 8];
        const short8 ar0 = *(const short8*)qr;
        const short8 ar1 = *(const short8*)(qr + 32);
        const ushort_t* kb = &krel[(size_t)l16 * 512 + n * 64 + quad * 8];
        int ntmin = w + 16 - 4 * nchunk; if (ntmin < 0) ntmin = 0;
        const int ntmax = w + 17 - 4 * c0;       // r <= 287 and only cols >= 64*c0
        const ushort_t* pb = kb + (size_t)ntmin * 8192;   // 16 rows * 512
        short8 br0 = *(const short8*)pb;
        short8 br1 = *(const short8*)(pb + 32);
#pragma unroll 1
        for (int nt = ntmin; nt < ntmax; ++nt) {
            short8 nb0, nb1;
            if (nt + 1 < ntmax) {
                const ushort_t* pn = kb + (size_t)(nt + 1) * 8192;
                nb0 = *(const short8*)pn;
                nb1 = *(const short8*)(pn + 32);
            }
            f32x4 acc = (f32x4){0.f, 0.f, 0.f, 0.f};
            acc = __builtin_amdgcn_mfma_f32_16x16x32_bf16(ar0, br0, acc, 0, 0, 0);
            acc = __builtin_amdgcn_mfma_f32_16x16x32_bf16(ar1, br1, acc, 0, 0, 0);
            const int r = nt * 16 + l16;
#pragma unroll
            for (int reg = 0; reg < 4; ++reg) {
                const int rowq = w * 16 + quad * 4 + reg;
                const int cs = rowq + 256 - r;
                if (cs >= 0) R_lds[rowq][cs] = (ushort_t)bf16r(acc[reg]);
            }
            br0 = nb0; br1 = nb1;
        }
    }

    f32x4 Oa[4];
#pragma unroll
    for (int nt = 0; nt < 4; ++nt) Oa[nt] = (f32x4){0.f, 0.f, 0.f, 0.f};
    float lpart[4] = {};

    const size_t vTbase = (size_t)((b * NH + n) * 64) * 2048;
    const int srow = tid >> 1, sc0 = (tid & 1) * 32;      // k/vT staging
    const short8 z8 = {0, 0, 0, 0, 0, 0, 0, 0};

    short8 kr[4], vr[4], kn[4], vn[4];

    auto issue = [&](int c, short8* kd, short8* vd) {
        const int jc0 = i0 - 256 + c * 64;
        const int jg = jc0 + srow;
        const bool okk = (jg >= 0);
        const ushort_t* ks = &kbuf[((size_t)b * S_ + jg) * 512 + n * 64 + sc0];
        const ushort_t* vs = &vT[vTbase + (size_t)srow * 2048 + jc0 + sc0];
#pragma unroll
        for (int u = 0; u < 4; ++u) {
            kd[u] = okk ? *(const short8*)(ks + u * 8) : z8;
            const bool okv = (jc0 + sc0 + u * 8) >= 0;
            vd[u] = okv ? *(const short8*)(vs + u * 8) : z8;
        }
    };

    issue(c0, kr, vr);

#pragma unroll 1
    for (int c = c0; c < nchunk; ++c) {
        const int jc0 = i0 - 256 + c * 64;
        __syncthreads();   // prev-chunk PV reads of k/vT done; c==c0: RG scatter done
#pragma unroll
        for (int u = 0; u < 4; ++u) {
            *(short8*)&k_lds[srow][sc0 + u * 8]  = kr[u];
            *(short8*)&vT_lds[srow][sc0 + u * 8] = vr[u];
        }
        if (c + 1 < nchunk) issue(c + 1, kn, vn);
        __syncthreads();

        // ---- QK ----
        f32x4 Sacc[4];
#pragma unroll
        for (int jt = 0; jt < 4; ++jt) {
            short8 bk0 = *(const short8*)&k_lds[jt * 16 + l16][quad * 8];
            short8 bk1 = *(const short8*)&k_lds[jt * 16 + l16][quad * 8 + 32];
            f32x4 s = (f32x4){0.f, 0.f, 0.f, 0.f};
            s = __builtin_amdgcn_mfma_f32_16x16x32_bf16(aq0, bk0, s, 0, 0, 0);
            s = __builtin_amdgcn_mfma_f32_16x16x32_bf16(aq1, bk1, s, 0, 0, 0);
            Sacc[jt] = s;
        }

        // ---- mask + rel bias + exp; p overlays R_lds in place ----
#pragma unroll
        for (int jt = 0; jt < 4; ++jt) {
#pragma unroll
            for (int reg = 0; reg < 4; ++reg) {
                const int row = w * 16 + quad * 4 + reg;
                const int i = i0 + row;
                const int j = jc0 + jt * 16 + l16;
                const int r = i - j;
                const bool valid = (j >= 0) && (j < xlen) && (r >= 0) && (r <= 256);
                float rvv = b2f(R_lds[row][c * 64 + jt * 16 + l16]);
                float e = valid ? __expf(Sacc[jt][reg] + rvv) : 0.f;
                lpart[reg] += e;
                R_lds[row][c * 64 + jt * 16 + l16] = (ushort_t)bf16r(e);
            }
        }
        __syncthreads();

        // ---- PV (p read from R_lds overlay) ----
        short8 ap0 = *(const short8*)&R_lds[w * 16 + l16][c * 64 + quad * 8];
        short8 ap1 = *(const short8*)&R_lds[w * 16 + l16][c * 64 + quad * 8 + 32];
#pragma unroll
        for (int nt = 0; nt < 4; ++nt) {
            short8 bv0 = *(const short8*)&vT_lds[nt * 16 + l16][quad * 8];
            short8 bv1 = *(const short8*)&vT_lds[nt * 16 + l16][quad * 8 + 32];
            Oa[nt] = __builtin_amdgcn_mfma_f32_16x16x32_bf16(ap0, bv0, Oa[nt], 0, 0, 0);
            Oa[nt] = __builtin_amdgcn_mfma_f32_16x16x32_bf16(ap1, bv1, Oa[nt], 0, 0, 0);
        }

        // ---- rotate register sets ----
#pragma unroll
        for (int u = 0; u < 4; ++u) { kr[u] = kn[u]; vr[u] = vn[u]; }
    }

#pragma unroll
    for (int reg = 0; reg < 4; ++reg) {
#pragma unroll
        for (int off = 1; off < 16; off <<= 1)
            lpart[reg] += __shfl_xor(lpart[reg], off, 64);
    }

#pragma unroll
    for (int reg = 0; reg < 4; ++reg) {
        const int i = i0 + w * 16 + quad * 4 + reg;
        const bool dead = (i >= xlen + 256);
        const float linv = 1.0f / lpart[reg];
#pragma unroll
        for (int nt = 0; nt < 4; ++nt) {
            const int d = n * 64 + nt * 16 + l16;
            float val = dead ? vmean[(size_t)b * 512 + d] : Oa[nt][reg] * linv;
            out[((size_t)b * S_ + i) * 512 + d] = val;
        }
    }
}

// ---------------------------------------------------------------------------
extern "C" void kernel_launch(void* const* d_in, const int* in_sizes, int n_in,
                              void* d_out, int out_size, void* d_ws, size_t ws_size,
                              hipStream_t stream) {
    const float* x     = (const float*)d_in[0];
    const float* Wq    = (const float*)d_in[1];
    const float* b_con = (const float*)d_in[2];
    const float* b_rel = (const float*)d_in[3];
    const float* Wk    = (const float*)d_in[4];
    const float* Wkr   = (const float*)d_in[5];
    const float* Wv    = (const float*)d_in[6];
    const float* bv    = (const float*)d_in[7];
    const int*   xlen  = (const int*)d_in[8];
    float* out = (float*)d_out;

    float* ws = (float*)d_ws;
    float* vmean = ws;                       // 1024 fp32
    ushort_t* ub   = (ushort_t*)(vmean + 1024);
    float* xpart   = (float*)ub;             // 64*512 fp32 (in old R3 region)
    ushort_t* qcon = ub   + 10485760;
    ushort_t* kbuf = qcon + 2097152;
    ushort_t* vT   = kbuf + 2097152;         // 1024 x 2048 bf16
    ushort_t* qrel = vT   + 2097152;
    ushort_t* xb16 = qrel + 2097152;         // 4096*512 bf16
    ushort_t* krel = xb16 + 2097152;         // 384*512 bf16
    ushort_t* pos  = krel + 196608;          // 384*512 bf16
    ushort_t* WTq  = pos  + 196608;          // 512*512 bf16 each
    ushort_t* WTk  = WTq + 262144;
    ushort_t* WTv  = WTk + 262144;
    ushort_t* WTkr = WTv + 262144;

    prep_kernel<<<dim3(8, 8, 7), 256, 0, stream>>>(x, Wq, Wk, Wv, Wkr,
                                                   WTq, WTk, WTv, WTkr, pos, xb16,
                                                   xpart);
    qkv_gemm<<<dim3(32, 26), 256, 0, stream>>>(xb16, WTq, WTk, WTv, pos, WTkr,
                                               b_con, b_rel, bv, xlen, xpart,
                                               qcon, qrel, kbuf, vT, krel, vmean);
    attn_kernel<<<dim3(64, 8, 2), 128, 0, stream>>>(qcon, qrel, kbuf, vT, krel,
                                                    vmean, xlen, out);
}

// Round 3
// 127.927 us; speedup vs baseline: 1.0670x; 1.0670x over previous
//
#include <hip/hip_runtime.h>
#include <math.h>

#define S_ 2048
#define NH 8
#define CSL 320       // R3 slots per row: cslot = j - (i&~63) + 256 in [0,320)
#define LP 72         // bf16 LDS row pitch: 144 B = 9*16 B -> b128-aligned

typedef __attribute__((ext_vector_type(8))) short short8;   // 8 x bf16 (4 VGPRs)
typedef __attribute__((ext_vector_type(4))) float f32x4;    // MFMA accumulator
typedef unsigned short ushort_t;

__device__ __forceinline__ short bf16r(float x) {   // RNE float->bf16
    union { float f; unsigned u; } v; v.f = x;
    unsigned r = v.u + 0x7fffu + ((v.u >> 16) & 1u);
    return (short)(r >> 16);
}
__device__ __forceinline__ float b2f(ushort_t h) {  // bf16->float
    union { float f; unsigned u; } v; v.u = ((unsigned)h) << 16; return v.f;
}

// ---------------------------------------------------------------------------
// Kernel 0: prep.  z<4: WT[n][k] = bf16(W[k][n]) (LDS-tiled 64x64).
// z==4: pos table bf16; rows 257..383 zero.  z==5: xb16 = bf16(x).
// ---------------------------------------------------------------------------
__global__ __launch_bounds__(256) void prep_kernel(
    const float* __restrict__ x,
    const float* __restrict__ Wq, const float* __restrict__ Wk,
    const float* __restrict__ Wv, const float* __restrict__ Wkr,
    ushort_t* __restrict__ WTq, ushort_t* __restrict__ WTk,
    ushort_t* __restrict__ WTv, ushort_t* __restrict__ WTkr,
    ushort_t* __restrict__ pos, ushort_t* __restrict__ xb16)
{
    const int widx = blockIdx.z;
    const int t = threadIdx.x;
    if (widx == 4) {
        const int base = blockIdx.y * 8 + blockIdx.x;    // 0..63
        const float C = -0.051905126482615036f;          // -log2(10000)/256
        const int f = t;
#pragma unroll
        for (int rep = 0; rep < 6; ++rep) {
            const int r = base + rep * 64;               // 0..383
            unsigned pk = 0;
            if (r <= 256) {
                float ang = (float)r * exp2f(C * (float)f);
                unsigned s = (unsigned)(ushort_t)bf16r(sinf(ang));
                unsigned c = (unsigned)(ushort_t)bf16r(cosf(ang));
                pk = s | (c << 16);
            }
            ((unsigned*)pos)[(size_t)r * 256 + f] = pk;
        }
        return;
    }
    if (widx == 5) {
        const int sub = blockIdx.y * 8 + blockIdx.x;     // 0..63
        const size_t base = (size_t)sub * 32768;
#pragma unroll
        for (int it = 0; it < 8; ++it) {
            const size_t idx = base + (size_t)it * 4096 + (size_t)t * 16;
            const float* src = &x[idx];
            ushort_t t16[16];
#pragma unroll
            for (int u = 0; u < 16; ++u) t16[u] = (ushort_t)bf16r(src[u]);
            *(short8*)&xb16[idx]     = *(short8*)&t16[0];
            *(short8*)&xb16[idx + 8] = *(short8*)&t16[8];
        }
        return;
    }
    const float* W = (widx == 0) ? Wq : (widx == 1) ? Wk : (widx == 2) ? Wv : Wkr;
    ushort_t* WT   = (widx == 0) ? WTq : (widx == 1) ? WTk : (widx == 2) ? WTv : WTkr;
    const int k0 = blockIdx.x * 64, n0 = blockIdx.y * 64;
    __shared__ __align__(16) ushort_t T[64][72];
    const int srow = t >> 2, sc0 = (t & 3) * 16;
    const float* src = &W[(size_t)(k0 + srow) * 512 + n0 + sc0];
#pragma unroll
    for (int u = 0; u < 16; ++u) T[sc0 + u][srow] = (ushort_t)bf16r(src[u]);
    __syncthreads();
    ushort_t* dst = &WT[(size_t)(n0 + srow) * 512 + k0 + sc0];
    *(short8*)dst       = *(const short8*)&T[srow][sc0];
    *(short8*)(dst + 8) = *(const short8*)&T[srow][sc0 + 8];
}

// ---------------------------------------------------------------------------
// Kernel 1: fused QKV (+krel) GEMM via bf16 MFMA.  Grid (32, 25).
// xlen-aware: q tiles with s0 >= xlen+256 are never read (dead rows ->
// vmean path); k tiles with s0 >= xlen+63 are never staged by attn.
// ---------------------------------------------------------------------------
__global__ __launch_bounds__(256) void qkv_gemm(
    const ushort_t* __restrict__ xb16,
    const ushort_t* __restrict__ WTq, const ushort_t* __restrict__ WTk,
    const ushort_t* __restrict__ WTv,
    const ushort_t* __restrict__ pos, const ushort_t* __restrict__ WTkr,
    const float* __restrict__ b_con, const float* __restrict__ b_rel,
    const float* __restrict__ bv, const int* __restrict__ xlen_p,
    ushort_t* __restrict__ qcon, ushort_t* __restrict__ qrel,
    ushort_t* __restrict__ kout, ushort_t* __restrict__ vT,
    ushort_t* __restrict__ krel)
{
    const int widx = blockIdx.y >> 3;
    const int tid = threadIdx.x, lane = tid & 63, w = tid >> 6;
    const int quad = lane >> 4, l16 = lane & 15;

    __shared__ __align__(16) ushort_t A_lds[128][40];
    __shared__ __align__(16) ushort_t B_lds[64][40];

    f32x4 acc[2][4];
#pragma unroll
    for (int mt = 0; mt < 2; ++mt)
#pragma unroll
        for (int nt = 0; nt < 4; ++nt) acc[mt][nt] = (f32x4){0.f, 0.f, 0.f, 0.f};

    const int arow = tid >> 1, ak0 = (tid & 1) * 16;
    const int brow = tid >> 2, bk0 = (tid & 3) * 8;

    if (widx < 2) {
        const int m0 = blockIdx.x * 128;
        // ---- xlen elision: rows are (b, s) = (m0>>11, m0&2047) ----
        {
            const int xl = xlen_p[m0 >> 11];
            const int s0 = m0 & 2047;
            if (widx == 0) { if (s0 >= xl + 256) return; }   // q rows dead
            else           { if (s0 >= xl + 63)  return; }   // k rows never staged
        }
        const int n0 = (blockIdx.y & 7) * 64;
        const ushort_t* WT = (widx == 0) ? WTq : WTk;
        const ushort_t* xrow = &xb16[(size_t)(m0 + arow) * 512 + ak0];
        const ushort_t* wrow = &WT[(size_t)(n0 + brow) * 512 + bk0];

        short8 pa0 = *(const short8*)xrow;
        short8 pa1 = *(const short8*)(xrow + 8);
        short8 pb  = *(const short8*)wrow;

#pragma unroll 1
        for (int k0 = 0; k0 < 512; k0 += 32) {
            __syncthreads();   // prev iter's MFMA LDS reads done
            *(short8*)&A_lds[arow][ak0]     = pa0;
            *(short8*)&A_lds[arow][ak0 + 8] = pa1;
            *(short8*)&B_lds[brow][bk0]     = pb;
            if (k0 < 480) {
                pa0 = *(const short8*)(xrow + k0 + 32);
                pa1 = *(const short8*)(xrow + k0 + 40);
                pb  = *(const short8*)(wrow + k0 + 32);
            }
            __syncthreads();
            short8 a0 = *(const short8*)&A_lds[w * 32 + l16][quad * 8];
            short8 a1 = *(const short8*)&A_lds[w * 32 + 16 + l16][quad * 8];
#pragma unroll
            for (int nt = 0; nt < 4; ++nt) {
                short8 bb = *(const short8*)&B_lds[nt * 16 + l16][quad * 8];
                acc[0][nt] = __builtin_amdgcn_mfma_f32_16x16x32_bf16(a0, bb, acc[0][nt], 0, 0, 0);
                acc[1][nt] = __builtin_amdgcn_mfma_f32_16x16x32_bf16(a1, bb, acc[1][nt], 0, 0, 0);
            }
        }

#pragma unroll
        for (int nt = 0; nt < 4; ++nt) {
            const int col = n0 + nt * 16 + l16;
            float bc = 0.f, br = 0.f;
            if (widx == 0) { bc = b_con[col]; br = b_rel[col]; }
#pragma unroll
            for (int mt = 0; mt < 2; ++mt) {
#pragma unroll
                for (int reg = 0; reg < 4; ++reg) {
                    const size_t m = (size_t)(m0 + w * 32 + mt * 16 + quad * 4 + reg);
                    const float val = acc[mt][nt][reg];
                    if (widx == 0) {
                        qcon[m * 512 + col] = (ushort_t)bf16r((val + bc) * 0.125f);
                        qrel[m * 512 + col] = (ushort_t)bf16r((val + br) * 0.125f);
                    } else {
                        kout[m * 512 + col] = (ushort_t)bf16r(val);
                    }
                }
            }
        }
    } else if (widx == 2) {
        // ---- V transposed mode: vT[d][j] = WTv[d] . x[j] + bv ----
        const int vb = (blockIdx.y & 7) * 32 + blockIdx.x;   // 0..255
        const int m0d = (vb & 3) * 128;                      // d tile
        const int n0j = (vb >> 2) * 64;                      // seq tile
        const ushort_t* wrow = &WTv[(size_t)(m0d + arow) * 512 + ak0];
        const ushort_t* xrow = &xb16[(size_t)(n0j + brow) * 512 + bk0];

        short8 pa0 = *(const short8*)wrow;
        short8 pa1 = *(const short8*)(wrow + 8);
        short8 pb  = *(const short8*)xrow;

#pragma unroll 1
        for (int k0 = 0; k0 < 512; k0 += 32) {
            __syncthreads();
            *(short8*)&A_lds[arow][ak0]     = pa0;
            *(short8*)&A_lds[arow][ak0 + 8] = pa1;
            *(short8*)&B_lds[brow][bk0]     = pb;
            if (k0 < 480) {
                pa0 = *(const short8*)(wrow + k0 + 32);
                pa1 = *(const short8*)(wrow + k0 + 40);
                pb  = *(const short8*)(xrow + k0 + 32);
            }
            __syncthreads();
            short8 a0 = *(const short8*)&A_lds[w * 32 + l16][quad * 8];
            short8 a1 = *(const short8*)&A_lds[w * 32 + 16 + l16][quad * 8];
#pragma unroll
            for (int nt = 0; nt < 4; ++nt) {
                short8 bb = *(const short8*)&B_lds[nt * 16 + l16][quad * 8];
                acc[0][nt] = __builtin_amdgcn_mfma_f32_16x16x32_bf16(a0, bb, acc[0][nt], 0, 0, 0);
                acc[1][nt] = __builtin_amdgcn_mfma_f32_16x16x32_bf16(a1, bb, acc[1][nt], 0, 0, 0);
            }
        }

        const int b = n0j >> 11;
#pragma unroll
        for (int mt = 0; mt < 2; ++mt) {
#pragma unroll
            for (int reg = 0; reg < 4; ++reg) {
                const int d = m0d + w * 32 + mt * 16 + quad * 4 + reg;  // 0..511
                const int n = d >> 6, dd = d & 63;
                const float bvv = bv[d];
#pragma unroll
                for (int nt = 0; nt < 4; ++nt) {
                    const int s = (n0j + nt * 16 + l16) & 2047;
                    vT[((size_t)((b * NH + n) * 64 + dd)) * 2048 + s] =
                        (ushort_t)bf16r(acc[mt][nt][reg] + bvv);
                }
            }
        }
    } else {
        // ---- krel mode (by == 24): krel = pos @ Wkr ----
        if (blockIdx.x >= 24) return;
        const int m0 = (blockIdx.x >> 3) * 128;              // 0..255
        const int n0 = (blockIdx.x & 7) * 64;
        const ushort_t* prow = &pos[(size_t)(m0 + arow) * 512 + ak0];
        const ushort_t* wrow = &WTkr[(size_t)(n0 + brow) * 512 + bk0];

        short8 pa0 = *(const short8*)prow;
        short8 pa1 = *(const short8*)(prow + 8);
        short8 pb  = *(const short8*)wrow;

#pragma unroll 1
        for (int k0 = 0; k0 < 512; k0 += 32) {
            __syncthreads();
            *(short8*)&A_lds[arow][ak0]     = pa0;
            *(short8*)&A_lds[arow][ak0 + 8] = pa1;
            *(short8*)&B_lds[brow][bk0]     = pb;
            if (k0 < 480) {
                pa0 = *(const short8*)(prow + k0 + 32);
                pa1 = *(const short8*)(prow + k0 + 40);
                pb  = *(const short8*)(wrow + k0 + 32);
            }
            __syncthreads();
            short8 a0 = *(const short8*)&A_lds[w * 32 + l16][quad * 8];
            short8 a1 = *(const short8*)&A_lds[w * 32 + 16 + l16][quad * 8];
#pragma unroll
            for (int nt = 0; nt < 4; ++nt) {
                short8 bb = *(const short8*)&B_lds[nt * 16 + l16][quad * 8];
                acc[0][nt] = __builtin_amdgcn_mfma_f32_16x16x32_bf16(a0, bb, acc[0][nt], 0, 0, 0);
                acc[1][nt] = __builtin_amdgcn_mfma_f32_16x16x32_bf16(a1, bb, acc[1][nt], 0, 0, 0);
            }
        }

#pragma unroll
        for (int nt = 0; nt < 4; ++nt) {
            const int col = n0 + nt * 16 + l16;
#pragma unroll
            for (int mt = 0; mt < 2; ++mt)
#pragma unroll
                for (int reg = 0; reg < 4; ++reg) {
                    const size_t m = (size_t)(m0 + w * 32 + mt * 16 + quad * 4 + reg);
                    krel[m * 512 + col] = (ushort_t)bf16r(acc[mt][nt][reg]);
                }
        }
    }
}

// ---------------------------------------------------------------------------
// Kernel 3: rel GEMM, writing R in attention's consumption layout.
// cslot = (i&63) + 256 - r  (64-row attn tiles): attn's (64-q tile, chunk c)
// R block is the contiguous panel rows i0..i0+63, cols c*64..c*64+63.
// xlen-aware: tiles with i0 >= xlen+256 never read by attn -> skip.
// Grid (17,8,2): tile<16 = GEMM; tile==16 = vmean fold.
// ---------------------------------------------------------------------------
__global__ __launch_bounds__(256) void rel_gemm(
    const ushort_t* __restrict__ qrel, const ushort_t* __restrict__ krel,
    const ushort_t* __restrict__ vT, const int* __restrict__ xlen_p,
    ushort_t* __restrict__ R3, float* __restrict__ vmean)
{
    const int tile = blockIdx.x, n = blockIdx.y, b = blockIdx.z;
    const int tid = threadIdx.x, lane = tid & 63, w = tid >> 6;
    const int quad = lane >> 4, l16 = lane & 15;

    __shared__ __align__(16) ushort_t A_lds[128][LP];
    __shared__ __align__(16) ushort_t B_lds[64][LP];

    if (tile == 16) {
        // ---- vmean: rows (b*8+n)*64 + d of vT, mean over 2048 ----
        const int row = tid >> 2, seg = tid & 3;
        const ushort_t* src = &vT[((size_t)((b * NH + n) * 64 + row)) * 2048 + seg * 512];
        float sum = 0.f;
        for (int it = 0; it < 64; ++it) {
            short8 h = *(const short8*)(src + it * 8);
#pragma unroll
            for (int u = 0; u < 8; ++u) sum += b2f((ushort_t)h[u]);
        }
        float* scratch = (float*)A_lds;
        scratch[row * 4 + seg] = sum;
        __syncthreads();
        if (tid < 64) {
            float s = scratch[tid * 4] + scratch[tid * 4 + 1]
                    + scratch[tid * 4 + 2] + scratch[tid * 4 + 3];
            vmean[(size_t)b * 512 + n * 64 + tid] = s * (1.0f / (float)S_);
        }
        return;
    }

    const int i0 = tile * 128;
    if (i0 >= xlen_p[b] + 256) return;     // all 128 rows dead -> R never read

    {
        const int srow = tid >> 1, sc0 = (tid & 1) * 32;
        const ushort_t* src = &qrel[((size_t)b * S_ + i0 + srow) * 512 + n * 64 + sc0];
#pragma unroll
        for (int u = 0; u < 4; ++u)
            *(short8*)&A_lds[srow][sc0 + u * 8] = *(const short8*)(src + u * 8);
    }

    const size_t rbase3 = (size_t)(b * NH + n) * S_ * CSL;
    const int srow2 = tid >> 2, sc2 = (tid & 3) * 16;

    short8 pb0, pb1;
    auto issueB = [&](int rc) {
        const ushort_t* src = &krel[(size_t)(rc * 64 + srow2) * 512 + n * 64 + sc2];
        pb0 = *(const short8*)src;
        pb1 = *(const short8*)(src + 8);
    };
    issueB(0);

#pragma unroll 1
    for (int rc = 0; rc < 5; ++rc) {
        __syncthreads();   // A visible (rc==0) / prev chunk's B reads done
        *(short8*)&B_lds[srow2][sc2]     = pb0;
        *(short8*)&B_lds[srow2][sc2 + 8] = pb1;
        if (rc < 4) issueB(rc + 1);
        __syncthreads();

        short8 a[2][2];
#pragma unroll
        for (int mt = 0; mt < 2; ++mt) {
            a[mt][0] = *(const short8*)&A_lds[w * 32 + mt * 16 + l16][quad * 8];
            a[mt][1] = *(const short8*)&A_lds[w * 32 + mt * 16 + l16][quad * 8 + 32];
        }
#pragma unroll
        for (int nt = 0; nt < 4; ++nt) {
            short8 b0 = *(const short8*)&B_lds[nt * 16 + l16][quad * 8];
            short8 b1 = *(const short8*)&B_lds[nt * 16 + l16][quad * 8 + 32];
            const int r = rc * 64 + nt * 16 + l16;
#pragma unroll
            for (int mt = 0; mt < 2; ++mt) {
                f32x4 s = (f32x4){0.f, 0.f, 0.f, 0.f};
                s = __builtin_amdgcn_mfma_f32_16x16x32_bf16(a[mt][0], b0, s, 0, 0, 0);
                s = __builtin_amdgcn_mfma_f32_16x16x32_bf16(a[mt][1], b1, s, 0, 0, 0);
                if (r <= 256) {
#pragma unroll
                    for (int reg = 0; reg < 4; ++reg) {
                        const int ig = i0 + w * 32 + mt * 16 + quad * 4 + reg;
                        const int cslot = (ig & 63) + 256 - r;   // 64-tile mapping
                        R3[rbase3 + (size_t)ig * CSL + cslot] = (ushort_t)bf16r(s[reg]);
                    }
                }
            }
        }
    }
}

// ---------------------------------------------------------------------------
// Kernel 5: banded attention via bf16 MFMA.  64-row tiles, 256 threads
// (4 waves x 16 rows), grid (32,8,2) = 512 blocks.  Halves k/vT/R staging
// traffic + barriers per output row vs 32-row tiles.  64-aligned tiles ->
// jc0 >= 0 for every processed chunk (no j<0 predication anywhere).
// LDS 36.9 KB.  xlen-aware: dead tiles fast-path to vmean; chunk count
// trimmed to jc0 < xlen.
// ---------------------------------------------------------------------------
__global__ __launch_bounds__(256) void attn_kernel(
    const ushort_t* __restrict__ qcon, const ushort_t* __restrict__ kbuf,
    const ushort_t* __restrict__ vT, const ushort_t* __restrict__ R3,
    const float* __restrict__ vmean, const int* __restrict__ xlen_p,
    float* __restrict__ out)
{
    const int bx = blockIdx.x;
    const int tile = ((bx & 7) << 2) | (bx >> 3);   // XCD swizzle, 32 tiles
    const int n = blockIdx.y, b = blockIdx.z;
    const int i0 = tile * 64;
    const int tid = threadIdx.x, lane = tid & 63, w = tid >> 6;
    const int quad = lane >> 4, l16 = lane & 15;
    const int xlen = xlen_p[b];

    // ---- dead-tile fast path: every row fully masked -> uniform softmax ----
    if (i0 >= xlen + 256) {
        const int row = tid >> 2, cf = (tid & 3) * 16;
        const float* vm = &vmean[(size_t)b * 512 + n * 64 + cf];
        float* dst = &out[((size_t)b * S_ + i0 + row) * 512 + n * 64 + cf];
#pragma unroll
        for (int u = 0; u < 16; u += 4)
            *(float4*)&dst[u] = *(const float4*)&vm[u];
        return;
    }
    int nchunk = (xlen - i0 + 256 + 63) >> 6;
    if (nchunk > 5) nchunk = 5;
    const int c0 = (i0 < 256) ? ((256 - i0) >> 6) : 0;   // first chunk with jc0 >= 0

    __shared__ __align__(16) ushort_t k_lds[64][LP];
    __shared__ __align__(16) ushort_t vT_lds[64][LP];
    __shared__ __align__(16) ushort_t p_lds[64][LP];
    __shared__ __align__(16) ushort_t Rl_lds[64][LP];

    // ---- Q-con fragments in registers: wave w owns rows w*16..w*16+15 ----
    const ushort_t* qc = &qcon[((size_t)b * S_ + i0 + w * 16 + l16) * 512 + n * 64 + quad * 8];
    const short8 aq0 = *(const short8*)qc;
    const short8 aq1 = *(const short8*)(qc + 32);

    f32x4 Oa[4];
#pragma unroll
    for (int nt = 0; nt < 4; ++nt) Oa[nt] = (f32x4){0.f, 0.f, 0.f, 0.f};
    float lpart[4] = {};

    const size_t rbase3 = (size_t)(b * NH + n) * S_ * CSL;
    const size_t vTbase = (size_t)((b * NH + n) * 64) * 2048;
    const int srow = tid >> 2, sc0 = (tid & 3) * 16;    // staging: 64 rows x 64 cols

    short8 kr[2], vr[2], rr[2], kn[2], vn[2], rn[2];

    auto issue = [&](int c, short8* kd, short8* vd, short8* rd) {
        const int jc0 = i0 - 256 + c * 64;              // >= 0 for c >= c0
        const ushort_t* ks = &kbuf[((size_t)b * S_ + jc0 + srow) * 512 + n * 64 + sc0];
        kd[0] = *(const short8*)ks;
        kd[1] = *(const short8*)(ks + 8);
        const ushort_t* vs = &vT[vTbase + (size_t)srow * 2048 + jc0 + sc0];
        vd[0] = *(const short8*)vs;
        vd[1] = *(const short8*)(vs + 8);
        const ushort_t* Rs = &R3[rbase3 + (size_t)(i0 + srow) * CSL + c * 64 + sc0];
        rd[0] = *(const short8*)Rs;
        rd[1] = *(const short8*)(Rs + 8);
    };

    issue(c0, kr, vr, rr);

#pragma unroll 1
    for (int c = c0; c < nchunk; ++c) {
        const int jc0 = i0 - 256 + c * 64;
        __syncthreads();   // prev-chunk PV reads of k/vT/p + exp reads of Rl done
        *(short8*)&k_lds[srow][sc0]      = kr[0];
        *(short8*)&k_lds[srow][sc0 + 8]  = kr[1];
        *(short8*)&vT_lds[srow][sc0]     = vr[0];
        *(short8*)&vT_lds[srow][sc0 + 8] = vr[1];
        *(short8*)&Rl_lds[srow][sc0]     = rr[0];
        *(short8*)&Rl_lds[srow][sc0 + 8] = rr[1];
        if (c + 1 < nchunk) issue(c + 1, kn, vn, rn);
        __syncthreads();

        // ---- QK ----
        f32x4 Sacc[4];
#pragma unroll
        for (int jt = 0; jt < 4; ++jt) {
            short8 bk0 = *(const short8*)&k_lds[jt * 16 + l16][quad * 8];
            short8 bk1 = *(const short8*)&k_lds[jt * 16 + l16][quad * 8 + 32];
            f32x4 s = (f32x4){0.f, 0.f, 0.f, 0.f};
            s = __builtin_amdgcn_mfma_f32_16x16x32_bf16(aq0, bk0, s, 0, 0, 0);
            s = __builtin_amdgcn_mfma_f32_16x16x32_bf16(aq1, bk1, s, 0, 0, 0);
            Sacc[jt] = s;
        }

        // ---- mask + rel bias + exp; p -> LDS bf16 ----
#pragma unroll
        for (int jt = 0; jt < 4; ++jt) {
#pragma unroll
            for (int reg = 0; reg < 4; ++reg) {
                const int row = w * 16 + quad * 4 + reg;
                const int i = i0 + row;
                const int j = jc0 + jt * 16 + l16;
                const int r = i - j;
                const bool valid = (j < xlen) && (r >= 0) && (r <= 256);
                float rvv = b2f(Rl_lds[row][jt * 16 + l16]);
                float e = valid ? __expf(Sacc[jt][reg] + rvv) : 0.f;
                lpart[reg] += e;
                p_lds[row][jt * 16 + l16] = (ushort_t)bf16r(e);
            }
        }
        __syncthreads();

        // ---- PV ----
        short8 ap0 = *(const short8*)&p_lds[w * 16 + l16][quad * 8];
        short8 ap1 = *(const short8*)&p_lds[w * 16 + l16][quad * 8 + 32];
#pragma unroll
        for (int nt = 0; nt < 4; ++nt) {
            short8 bv0 = *(const short8*)&vT_lds[nt * 16 + l16][quad * 8];
            short8 bv1 = *(const short8*)&vT_lds[nt * 16 + l16][quad * 8 + 32];
            Oa[nt] = __builtin_amdgcn_mfma_f32_16x16x32_bf16(ap0, bv0, Oa[nt], 0, 0, 0);
            Oa[nt] = __builtin_amdgcn_mfma_f32_16x16x32_bf16(ap1, bv1, Oa[nt], 0, 0, 0);
        }

        // ---- rotate register sets ----
        kr[0] = kn[0]; kr[1] = kn[1];
        vr[0] = vn[0]; vr[1] = vn[1];
        rr[0] = rn[0]; rr[1] = rn[1];
    }

#pragma unroll
    for (int reg = 0; reg < 4; ++reg) {
#pragma unroll
        for (int off = 1; off < 16; off <<= 1)
            lpart[reg] += __shfl_xor(lpart[reg], off, 64);
    }

#pragma unroll
    for (int reg = 0; reg < 4; ++reg) {
        const int i = i0 + w * 16 + quad * 4 + reg;
        const bool dead = (i >= xlen + 256);
        const float linv = 1.0f / lpart[reg];
#pragma unroll
        for (int nt = 0; nt < 4; ++nt) {
            const int d = n * 64 + nt * 16 + l16;
            float val = dead ? vmean[(size_t)b * 512 + d] : Oa[nt][reg] * linv;
            out[((size_t)b * S_ + i) * 512 + d] = val;
        }
    }
}

// ---------------------------------------------------------------------------
extern "C" void kernel_launch(void* const* d_in, const int* in_sizes, int n_in,
                              void* d_out, int out_size, void* d_ws, size_t ws_size,
                              hipStream_t stream) {
    const float* x     = (const float*)d_in[0];
    const float* Wq    = (const float*)d_in[1];
    const float* b_con = (const float*)d_in[2];
    const float* b_rel = (const float*)d_in[3];
    const float* Wk    = (const float*)d_in[4];
    const float* Wkr   = (const float*)d_in[5];
    const float* Wv    = (const float*)d_in[6];
    const float* bv    = (const float*)d_in[7];
    const int*   xlen  = (const int*)d_in[8];
    float* out = (float*)d_out;

    float* ws = (float*)d_ws;
    float* vmean = ws;                       // 1024 fp32
    ushort_t* ub   = (ushort_t*)(vmean + 1024);
    ushort_t* R3   = ub;                     // 16*2048*320 bf16 = 21 MB
    ushort_t* qcon = R3   + 10485760;
    ushort_t* kbuf = qcon + 2097152;
    ushort_t* vT   = kbuf + 2097152;         // 1024 x 2048 bf16
    ushort_t* qrel = vT   + 2097152;
    ushort_t* xb16 = qrel + 2097152;         // 4096*512 bf16
    ushort_t* krel = xb16 + 2097152;         // 384*512 bf16
    ushort_t* pos  = krel + 196608;          // 384*512 bf16
    ushort_t* WTq  = pos  + 196608;          // 512*512 bf16 each
    ushort_t* WTk  = WTq + 262144;
    ushort_t* WTv  = WTk + 262144;
    ushort_t* WTkr = WTv + 262144;

    prep_kernel<<<dim3(8, 8, 6), 256, 0, stream>>>(x, Wq, Wk, Wv, Wkr,
                                                   WTq, WTk, WTv, WTkr, pos, xb16);
    qkv_gemm<<<dim3(32, 25), 256, 0, stream>>>(xb16, WTq, WTk, WTv, pos, WTkr,
                                               b_con, b_rel, bv, xlen,
                                               qcon, qrel, kbuf, vT, krel);
    rel_gemm<<<dim3(17, 8, 2), 256, 0, stream>>>(qrel, krel, vT, xlen, R3, vmean);
    attn_kernel<<<dim3(32, 8, 2), 256, 0, stream>>>(qcon, kbuf, vT, R3, vmean,
                                                    xlen, out);
}

// Round 6
// 127.393 us; speedup vs baseline: 1.0715x; 1.0042x over previous
//
#include <hip/hip_runtime.h>
#include <math.h>

#define S_ 2048
#define NH 8
#define CSL 320       // R3 slots per row: cslot = (i&63) + 256 - r in [0,320)
#define LP 72         // bf16 LDS row pitch: 144 B = 9*16 B -> b128-aligned

typedef __attribute__((ext_vector_type(8))) short short8;   // 8 x bf16 (4 VGPRs)
typedef __attribute__((ext_vector_type(4))) float f32x4;    // MFMA accumulator
typedef unsigned short ushort_t;

__device__ __forceinline__ short bf16r(float x) {   // RNE float->bf16
    union { float f; unsigned u; } v; v.f = x;
    unsigned r = v.u + 0x7fffu + ((v.u >> 16) & 1u);
    return (short)(r >> 16);
}
__device__ __forceinline__ float b2f(ushort_t h) {  // bf16->float
    union { float f; unsigned u; } v; v.u = ((unsigned)h) << 16; return v.f;
}

// ---------------------------------------------------------------------------
// Kernel 0: prep.  z<4: WT[n][k] = bf16(W[k][n]) (LDS-tiled 64x64).
// z==4: pos table bf16; rows 257..383 zero.  z==5: xb16 = bf16(x).
// ---------------------------------------------------------------------------
__global__ __launch_bounds__(256) void prep_kernel(
    const float* __restrict__ x,
    const float* __restrict__ Wq, const float* __restrict__ Wk,
    const float* __restrict__ Wv, const float* __restrict__ Wkr,
    ushort_t* __restrict__ WTq, ushort_t* __restrict__ WTk,
    ushort_t* __restrict__ WTv, ushort_t* __restrict__ WTkr,
    ushort_t* __restrict__ pos, ushort_t* __restrict__ xb16)
{
    const int widx = blockIdx.z;
    const int t = threadIdx.x;
    if (widx == 4) {
        const int base = blockIdx.y * 8 + blockIdx.x;    // 0..63
        const float C = -0.051905126482615036f;          // -log2(10000)/256
        const int f = t;
#pragma unroll
        for (int rep = 0; rep < 6; ++rep) {
            const int r = base + rep * 64;               // 0..383
            unsigned pk = 0;
            if (r <= 256) {
                float ang = (float)r * exp2f(C * (float)f);
                unsigned s = (unsigned)(ushort_t)bf16r(sinf(ang));
                unsigned c = (unsigned)(ushort_t)bf16r(cosf(ang));
                pk = s | (c << 16);
            }
            ((unsigned*)pos)[(size_t)r * 256 + f] = pk;
        }
        return;
    }
    if (widx == 5) {
        const int sub = blockIdx.y * 8 + blockIdx.x;     // 0..63
        const size_t base = (size_t)sub * 32768;
#pragma unroll
        for (int it = 0; it < 8; ++it) {
            const size_t idx = base + (size_t)it * 4096 + (size_t)t * 16;
            const float* src = &x[idx];
            ushort_t t16[16];
#pragma unroll
            for (int u = 0; u < 16; ++u) t16[u] = (ushort_t)bf16r(src[u]);
            *(short8*)&xb16[idx]     = *(short8*)&t16[0];
            *(short8*)&xb16[idx + 8] = *(short8*)&t16[8];
        }
        return;
    }
    const float* W = (widx == 0) ? Wq : (widx == 1) ? Wk : (widx == 2) ? Wv : Wkr;
    ushort_t* WT   = (widx == 0) ? WTq : (widx == 1) ? WTk : (widx == 2) ? WTv : WTkr;
    const int k0 = blockIdx.x * 64, n0 = blockIdx.y * 64;
    __shared__ __align__(16) ushort_t T[64][72];
    const int srow = t >> 2, sc0 = (t & 3) * 16;
    const float* src = &W[(size_t)(k0 + srow) * 512 + n0 + sc0];
#pragma unroll
    for (int u = 0; u < 16; ++u) T[sc0 + u][srow] = (ushort_t)bf16r(src[u]);
    __syncthreads();
    ushort_t* dst = &WT[(size_t)(n0 + srow) * 512 + k0 + sc0];
    *(short8*)dst       = *(const short8*)&T[srow][sc0];
    *(short8*)(dst + 8) = *(const short8*)&T[srow][sc0 + 8];
}

// ---------------------------------------------------------------------------
// Kernel 1: fused QKV (+krel) GEMM via bf16 MFMA.  Grid (32, 25).
// xlen-aware: q tiles with s0 >= xlen+256 are never read (dead rows ->
// vmean path); k tiles with s0 >= xlen+63 are never staged by attn.
// ---------------------------------------------------------------------------
__global__ __launch_bounds__(256) void qkv_gemm(
    const ushort_t* __restrict__ xb16,
    const ushort_t* __restrict__ WTq, const ushort_t* __restrict__ WTk,
    const ushort_t* __restrict__ WTv,
    const ushort_t* __restrict__ pos, const ushort_t* __restrict__ WTkr,
    const float* __restrict__ b_con, const float* __restrict__ b_rel,
    const float* __restrict__ bv, const int* __restrict__ xlen_p,
    ushort_t* __restrict__ qcon, ushort_t* __restrict__ qrel,
    ushort_t* __restrict__ kout, ushort_t* __restrict__ vT,
    ushort_t* __restrict__ krel)
{
    const int widx = blockIdx.y >> 3;
    const int tid = threadIdx.x, lane = tid & 63, w = tid >> 6;
    const int quad = lane >> 4, l16 = lane & 15;

    __shared__ __align__(16) ushort_t A_lds[128][40];
    __shared__ __align__(16) ushort_t B_lds[64][40];

    f32x4 acc[2][4];
#pragma unroll
    for (int mt = 0; mt < 2; ++mt)
#pragma unroll
        for (int nt = 0; nt < 4; ++nt) acc[mt][nt] = (f32x4){0.f, 0.f, 0.f, 0.f};

    const int arow = tid >> 1, ak0 = (tid & 1) * 16;
    const int brow = tid >> 2, bk0 = (tid & 3) * 8;

    if (widx < 2) {
        const int m0 = blockIdx.x * 128;
        // ---- xlen elision: rows are (b, s) = (m0>>11, m0&2047) ----
        {
            const int xl = xlen_p[m0 >> 11];
            const int s0 = m0 & 2047;
            if (widx == 0) { if (s0 >= xl + 256) return; }   // q rows dead
            else           { if (s0 >= xl + 63)  return; }   // k rows never staged
        }
        const int n0 = (blockIdx.y & 7) * 64;
        const ushort_t* WT = (widx == 0) ? WTq : WTk;
        const ushort_t* xrow = &xb16[(size_t)(m0 + arow) * 512 + ak0];
        const ushort_t* wrow = &WT[(size_t)(n0 + brow) * 512 + bk0];

        short8 pa0 = *(const short8*)xrow;
        short8 pa1 = *(const short8*)(xrow + 8);
        short8 pb  = *(const short8*)wrow;

#pragma unroll 1
        for (int k0 = 0; k0 < 512; k0 += 32) {
            __syncthreads();   // prev iter's MFMA LDS reads done
            *(short8*)&A_lds[arow][ak0]     = pa0;
            *(short8*)&A_lds[arow][ak0 + 8] = pa1;
            *(short8*)&B_lds[brow][bk0]     = pb;
            if (k0 < 480) {
                pa0 = *(const short8*)(xrow + k0 + 32);
                pa1 = *(const short8*)(xrow + k0 + 40);
                pb  = *(const short8*)(wrow + k0 + 32);
            }
            __syncthreads();
            short8 a0 = *(const short8*)&A_lds[w * 32 + l16][quad * 8];
            short8 a1 = *(const short8*)&A_lds[w * 32 + 16 + l16][quad * 8];
#pragma unroll
            for (int nt = 0; nt < 4; ++nt) {
                short8 bb = *(const short8*)&B_lds[nt * 16 + l16][quad * 8];
                acc[0][nt] = __builtin_amdgcn_mfma_f32_16x16x32_bf16(a0, bb, acc[0][nt], 0, 0, 0);
                acc[1][nt] = __builtin_amdgcn_mfma_f32_16x16x32_bf16(a1, bb, acc[1][nt], 0, 0, 0);
            }
        }

#pragma unroll
        for (int nt = 0; nt < 4; ++nt) {
            const int col = n0 + nt * 16 + l16;
            float bc = 0.f, br = 0.f;
            if (widx == 0) { bc = b_con[col]; br = b_rel[col]; }
#pragma unroll
            for (int mt = 0; mt < 2; ++mt) {
#pragma unroll
                for (int reg = 0; reg < 4; ++reg) {
                    const size_t m = (size_t)(m0 + w * 32 + mt * 16 + quad * 4 + reg);
                    const float val = acc[mt][nt][reg];
                    if (widx == 0) {
                        qcon[m * 512 + col] = (ushort_t)bf16r((val + bc) * 0.125f);
                        qrel[m * 512 + col] = (ushort_t)bf16r((val + br) * 0.125f);
                    } else {
                        kout[m * 512 + col] = (ushort_t)bf16r(val);
                    }
                }
            }
        }
    } else if (widx == 2) {
        // ---- V transposed mode: vT[d][j] = WTv[d] . x[j] + bv ----
        const int vb = (blockIdx.y & 7) * 32 + blockIdx.x;   // 0..255
        const int m0d = (vb & 3) * 128;                      // d tile
        const int n0j = (vb >> 2) * 64;                      // seq tile
        const ushort_t* wrow = &WTv[(size_t)(m0d + arow) * 512 + ak0];
        const ushort_t* xrow = &xb16[(size_t)(n0j + brow) * 512 + bk0];

        short8 pa0 = *(const short8*)wrow;
        short8 pa1 = *(const short8*)(wrow + 8);
        short8 pb  = *(const short8*)xrow;

#pragma unroll 1
        for (int k0 = 0; k0 < 512; k0 += 32) {
            __syncthreads();
            *(short8*)&A_lds[arow][ak0]     = pa0;
            *(short8*)&A_lds[arow][ak0 + 8] = pa1;
            *(short8*)&B_lds[brow][bk0]     = pb;
            if (k0 < 480) {
                pa0 = *(const short8*)(wrow + k0 + 32);
                pa1 = *(const short8*)(wrow + k0 + 40);
                pb  = *(const short8*)(xrow + k0 + 32);
            }
            __syncthreads();
            short8 a0 = *(const short8*)&A_lds[w * 32 + l16][quad * 8];
            short8 a1 = *(const short8*)&A_lds[w * 32 + 16 + l16][quad * 8];
#pragma unroll
            for (int nt = 0; nt < 4; ++nt) {
                short8 bb = *(const short8*)&B_lds[nt * 16 + l16][quad * 8];
                acc[0][nt] = __builtin_amdgcn_mfma_f32_16x16x32_bf16(a0, bb, acc[0][nt], 0, 0, 0);
                acc[1][nt] = __builtin_amdgcn_mfma_f32_16x16x32_bf16(a1, bb, acc[1][nt], 0, 0, 0);
            }
        }

        const int b = n0j >> 11;
#pragma unroll
        for (int mt = 0; mt < 2; ++mt) {
#pragma unroll
            for (int reg = 0; reg < 4; ++reg) {
                const int d = m0d + w * 32 + mt * 16 + quad * 4 + reg;  // 0..511
                const int n = d >> 6, dd = d & 63;
                const float bvv = bv[d];
#pragma unroll
                for (int nt = 0; nt < 4; ++nt) {
                    const int s = (n0j + nt * 16 + l16) & 2047;
                    vT[((size_t)((b * NH + n) * 64 + dd)) * 2048 + s] =
                        (ushort_t)bf16r(acc[mt][nt][reg] + bvv);
                }
            }
        }
    } else {
        // ---- krel mode (by == 24): krel = pos @ Wkr ----
        if (blockIdx.x >= 24) return;
        const int m0 = (blockIdx.x >> 3) * 128;              // 0..255
        const int n0 = (blockIdx.x & 7) * 64;
        const ushort_t* prow = &pos[(size_t)(m0 + arow) * 512 + ak0];
        const ushort_t* wrow = &WTkr[(size_t)(n0 + brow) * 512 + bk0];

        short8 pa0 = *(const short8*)prow;
        short8 pa1 = *(const short8*)(prow + 8);
        short8 pb  = *(const short8*)wrow;

#pragma unroll 1
        for (int k0 = 0; k0 < 512; k0 += 32) {
            __syncthreads();
            *(short8*)&A_lds[arow][ak0]     = pa0;
            *(short8*)&A_lds[arow][ak0 + 8] = pa1;
            *(short8*)&B_lds[brow][bk0]     = pb;
            if (k0 < 480) {
                pa0 = *(const short8*)(prow + k0 + 32);
                pa1 = *(const short8*)(prow + k0 + 40);
                pb  = *(const short8*)(wrow + k0 + 32);
            }
            __syncthreads();
            short8 a0 = *(const short8*)&A_lds[w * 32 + l16][quad * 8];
            short8 a1 = *(const short8*)&A_lds[w * 32 + 16 + l16][quad * 8];
#pragma unroll
            for (int nt = 0; nt < 4; ++nt) {
                short8 bb = *(const short8*)&B_lds[nt * 16 + l16][quad * 8];
                acc[0][nt] = __builtin_amdgcn_mfma_f32_16x16x32_bf16(a0, bb, acc[0][nt], 0, 0, 0);
                acc[1][nt] = __builtin_amdgcn_mfma_f32_16x16x32_bf16(a1, bb, acc[1][nt], 0, 0, 0);
            }
        }

#pragma unroll
        for (int nt = 0; nt < 4; ++nt) {
            const int col = n0 + nt * 16 + l16;
#pragma unroll
            for (int mt = 0; mt < 2; ++mt)
#pragma unroll
                for (int reg = 0; reg < 4; ++reg) {
                    const size_t m = (size_t)(m0 + w * 32 + mt * 16 + quad * 4 + reg);
                    krel[m * 512 + col] = (ushort_t)bf16r(acc[mt][nt][reg]);
                }
        }
    }
}

// ---------------------------------------------------------------------------
// Kernel 3: rel GEMM, writing R in attention's consumption layout.
// cslot = (i&63) + 256 - r  (64-row attn tiles): attn's (64-q tile, chunk c)
// R block is the contiguous panel rows i0..i0+63, cols c*64..c*64+63.
// xlen-aware: tiles with i0 >= xlen+256 never read by attn -> skip.
// Grid (17,8,2): tile<16 = GEMM; tile==16 = vmean fold.
// ---------------------------------------------------------------------------
__global__ __launch_bounds__(256) void rel_gemm(
    const ushort_t* __restrict__ qrel, const ushort_t* __restrict__ krel,
    const ushort_t* __restrict__ vT, const int* __restrict__ xlen_p,
    ushort_t* __restrict__ R3, float* __restrict__ vmean)
{
    const int tile = blockIdx.x, n = blockIdx.y, b = blockIdx.z;
    const int tid = threadIdx.x, lane = tid & 63, w = tid >> 6;
    const int quad = lane >> 4, l16 = lane & 15;

    __shared__ __align__(16) ushort_t A_lds[128][LP];
    __shared__ __align__(16) ushort_t B_lds[64][LP];

    if (tile == 16) {
        // ---- vmean: rows (b*8+n)*64 + d of vT, mean over 2048 ----
        const int row = tid >> 2, seg = tid & 3;
        const ushort_t* src = &vT[((size_t)((b * NH + n) * 64 + row)) * 2048 + seg * 512];
        float sum = 0.f;
        for (int it = 0; it < 64; ++it) {
            short8 h = *(const short8*)(src + it * 8);
#pragma unroll
            for (int u = 0; u < 8; ++u) sum += b2f((ushort_t)h[u]);
        }
        float* scratch = (float*)A_lds;
        scratch[row * 4 + seg] = sum;
        __syncthreads();
        if (tid < 64) {
            float s = scratch[tid * 4] + scratch[tid * 4 + 1]
                    + scratch[tid * 4 + 2] + scratch[tid * 4 + 3];
            vmean[(size_t)b * 512 + n * 64 + tid] = s * (1.0f / (float)S_);
        }
        return;
    }

    const int i0 = tile * 128;
    if (i0 >= xlen_p[b] + 256) return;     // all 128 rows dead -> R never read

    {
        const int srow = tid >> 1, sc0 = (tid & 1) * 32;
        const ushort_t* src = &qrel[((size_t)b * S_ + i0 + srow) * 512 + n * 64 + sc0];
#pragma unroll
        for (int u = 0; u < 4; ++u)
            *(short8*)&A_lds[srow][sc0 + u * 8] = *(const short8*)(src + u * 8);
    }

    const size_t rbase3 = (size_t)(b * NH + n) * S_ * CSL;
    const int srow2 = tid >> 2, sc2 = (tid & 3) * 16;

    short8 pb0, pb1;
    auto issueB = [&](int rc) {
        const ushort_t* src = &krel[(size_t)(rc * 64 + srow2) * 512 + n * 64 + sc2];
        pb0 = *(const short8*)src;
        pb1 = *(const short8*)(src + 8);
    };
    issueB(0);

#pragma unroll 1
    for (int rc = 0; rc < 5; ++rc) {
        __syncthreads();   // A visible (rc==0) / prev chunk's B reads done
        *(short8*)&B_lds[srow2][sc2]     = pb0;
        *(short8*)&B_lds[srow2][sc2 + 8] = pb1;
        if (rc < 4) issueB(rc + 1);
        __syncthreads();

        short8 a[2][2];
#pragma unroll
        for (int mt = 0; mt < 2; ++mt) {
            a[mt][0] = *(const short8*)&A_lds[w * 32 + mt * 16 + l16][quad * 8];
            a[mt][1] = *(const short8*)&A_lds[w * 32 + mt * 16 + l16][quad * 8 + 32];
        }
#pragma unroll
        for (int nt = 0; nt < 4; ++nt) {
            short8 b0 = *(const short8*)&B_lds[nt * 16 + l16][quad * 8];
            short8 b1 = *(const short8*)&B_lds[nt * 16 + l16][quad * 8 + 32];
            const int r = rc * 64 + nt * 16 + l16;
#pragma unroll
            for (int mt = 0; mt < 2; ++mt) {
                f32x4 s = (f32x4){0.f, 0.f, 0.f, 0.f};
                s = __builtin_amdgcn_mfma_f32_16x16x32_bf16(a[mt][0], b0, s, 0, 0, 0);
                s = __builtin_amdgcn_mfma_f32_16x16x32_bf16(a[mt][1], b1, s, 0, 0, 0);
                if (r <= 256) {
#pragma unroll
                    for (int reg = 0; reg < 4; ++reg) {
                        const int ig = i0 + w * 32 + mt * 16 + quad * 4 + reg;
                        const int cslot = (ig & 63) + 256 - r;   // 64-tile mapping
                        R3[rbase3 + (size_t)ig * CSL + cslot] = (ushort_t)bf16r(s[reg]);
                    }
                }
            }
        }
    }
}

// ---------------------------------------------------------------------------
// Kernel 5: banded attention.  64-row tiles, 256 threads, grid (32,8,2).
// Change vs R3: p overlays Rl_lds in place (p rows are wave-local: wave w
// writes and PV-reads only rows w*16..w*16+15) -> p_lds removed and the
// exp->PV barrier removed.  2 barriers/chunk, LDS 27.7 KB (5 blocks/CU).
// ---------------------------------------------------------------------------
__global__ __launch_bounds__(256) void attn_kernel(
    const ushort_t* __restrict__ qcon, const ushort_t* __restrict__ kbuf,
    const ushort_t* __restrict__ vT, const ushort_t* __restrict__ R3,
    const float* __restrict__ vmean, const int* __restrict__ xlen_p,
    float* __restrict__ out)
{
    const int bx = blockIdx.x;
    const int tile = ((bx & 7) << 2) | (bx >> 3);   // XCD swizzle, 32 tiles
    const int n = blockIdx.y, b = blockIdx.z;
    const int i0 = tile * 64;
    const int tid = threadIdx.x, lane = tid & 63, w = tid >> 6;
    const int quad = lane >> 4, l16 = lane & 15;
    const int xlen = xlen_p[b];

    // ---- dead-tile fast path: every row fully masked -> uniform softmax ----
    if (i0 >= xlen + 256) {
        const int row = tid >> 2, cf = (tid & 3) * 16;
        const float* vm = &vmean[(size_t)b * 512 + n * 64 + cf];
        float* dst = &out[((size_t)b * S_ + i0 + row) * 512 + n * 64 + cf];
#pragma unroll
        for (int u = 0; u < 16; u += 4)
            *(float4*)&dst[u] = *(const float4*)&vm[u];
        return;
    }
    int nchunk = (xlen - i0 + 256 + 63) >> 6;
    if (nchunk > 5) nchunk = 5;
    const int c0 = (i0 < 256) ? ((256 - i0) >> 6) : 0;   // first chunk with jc0 >= 0

    __shared__ __align__(16) ushort_t k_lds[64][LP];
    __shared__ __align__(16) ushort_t vT_lds[64][LP];
    __shared__ __align__(16) ushort_t Rl_lds[64][LP];    // R, overlaid by p

    // ---- Q-con fragments in registers: wave w owns rows w*16..w*16+15 ----
    const ushort_t* qc = &qcon[((size_t)b * S_ + i0 + w * 16 + l16) * 512 + n * 64 + quad * 8];
    const short8 aq0 = *(const short8*)qc;
    const short8 aq1 = *(const short8*)(qc + 32);

    f32x4 Oa[4];
#pragma unroll
    for (int nt = 0; nt < 4; ++nt) Oa[nt] = (f32x4){0.f, 0.f, 0.f, 0.f};
    float lpart[4] = {};

    const size_t rbase3 = (size_t)(b * NH + n) * S_ * CSL;
    const size_t vTbase = (size_t)((b * NH + n) * 64) * 2048;
    const int srow = tid >> 2, sc0 = (tid & 3) * 16;    // staging: 64 rows x 64 cols

    short8 kr[2], vr[2], rr[2], kn[2], vn[2], rn[2];

    auto issue = [&](int c, short8* kd, short8* vd, short8* rd) {
        const int jc0 = i0 - 256 + c * 64;              // >= 0 for c >= c0
        const ushort_t* ks = &kbuf[((size_t)b * S_ + jc0 + srow) * 512 + n * 64 + sc0];
        kd[0] = *(const short8*)ks;
        kd[1] = *(const short8*)(ks + 8);
        const ushort_t* vs = &vT[vTbase + (size_t)srow * 2048 + jc0 + sc0];
        vd[0] = *(const short8*)vs;
        vd[1] = *(const short8*)(vs + 8);
        const ushort_t* Rs = &R3[rbase3 + (size_t)(i0 + srow) * CSL + c * 64 + sc0];
        rd[0] = *(const short8*)Rs;
        rd[1] = *(const short8*)(Rs + 8);
    };

    issue(c0, kr, vr, rr);

#pragma unroll 1
    for (int c = c0; c < nchunk; ++c) {
        const int jc0 = i0 - 256 + c * 64;
        __syncthreads();   // prev-chunk PV/exp reads of k/vT/Rl done
        *(short8*)&k_lds[srow][sc0]      = kr[0];
        *(short8*)&k_lds[srow][sc0 + 8]  = kr[1];
        *(short8*)&vT_lds[srow][sc0]     = vr[0];
        *(short8*)&vT_lds[srow][sc0 + 8] = vr[1];
        *(short8*)&Rl_lds[srow][sc0]     = rr[0];
        *(short8*)&Rl_lds[srow][sc0 + 8] = rr[1];
        if (c + 1 < nchunk) issue(c + 1, kn, vn, rn);
        __syncthreads();

        // ---- QK ----
        f32x4 Sacc[4];
#pragma unroll
        for (int jt = 0; jt < 4; ++jt) {
            short8 bk0 = *(const short8*)&k_lds[jt * 16 + l16][quad * 8];
            short8 bk1 = *(const short8*)&k_lds[jt * 16 + l16][quad * 8 + 32];
            f32x4 s = (f32x4){0.f, 0.f, 0.f, 0.f};
            s = __builtin_amdgcn_mfma_f32_16x16x32_bf16(aq0, bk0, s, 0, 0, 0);
            s = __builtin_amdgcn_mfma_f32_16x16x32_bf16(aq1, bk1, s, 0, 0, 0);
            Sacc[jt] = s;
        }

        // ---- mask + rel bias + exp; p overwrites Rl slot (wave-local rows)
#pragma unroll
        for (int jt = 0; jt < 4; ++jt) {
#pragma unroll
            for (int reg = 0; reg < 4; ++reg) {
                const int row = w * 16 + quad * 4 + reg;
                const int i = i0 + row;
                const int j = jc0 + jt * 16 + l16;
                const int r = i - j;
                const bool valid = (j < xlen) && (r >= 0) && (r <= 256);
                float rvv = b2f(Rl_lds[row][jt * 16 + l16]);
                float e = valid ? __expf(Sacc[jt][reg] + rvv) : 0.f;
                lpart[reg] += e;
                Rl_lds[row][jt * 16 + l16] = (ushort_t)bf16r(e);
            }
        }
        // no barrier: p rows are wave-local (written+read by the same wave)

        // ---- PV (p read from Rl overlay) ----
        short8 ap0 = *(const short8*)&Rl_lds[w * 16 + l16][quad * 8];
        short8 ap1 = *(const short8*)&Rl_lds[w * 16 + l16][quad * 8 + 32];
#pragma unroll
        for (int nt = 0; nt < 4; ++nt) {
            short8 bv0 = *(const short8*)&vT_lds[nt * 16 + l16][quad * 8];
            short8 bv1 = *(const short8*)&vT_lds[nt * 16 + l16][quad * 8 + 32];
            Oa[nt] = __builtin_amdgcn_mfma_f32_16x16x32_bf16(ap0, bv0, Oa[nt], 0, 0, 0);
            Oa[nt] = __builtin_amdgcn_mfma_f32_16x16x32_bf16(ap1, bv1, Oa[nt], 0, 0, 0);
        }

        // ---- rotate register sets ----
        kr[0] = kn[0]; kr[1] = kn[1];
        vr[0] = vn[0]; vr[1] = vn[1];
        rr[0] = rn[0]; rr[1] = rn[1];
    }

#pragma unroll
    for (int reg = 0; reg < 4; ++reg) {
#pragma unroll
        for (int off = 1; off < 16; off <<= 1)
            lpart[reg] += __shfl_xor(lpart[reg], off, 64);
    }

#pragma unroll
    for (int reg = 0; reg < 4; ++reg) {
        const int i = i0 + w * 16 + quad * 4 + reg;
        const bool dead = (i >= xlen + 256);
        const float linv = 1.0f / lpart[reg];
#pragma unroll
        for (int nt = 0; nt < 4; ++nt) {
            const int d = n * 64 + nt * 16 + l16;
            float val = dead ? vmean[(size_t)b * 512 + d] : Oa[nt][reg] * linv;
            out[((size_t)b * S_ + i) * 512 + d] = val;
        }
    }
}

// ---------------------------------------------------------------------------
extern "C" void kernel_launch(void* const* d_in, const int* in_sizes, int n_in,
                              void* d_out, int out_size, void* d_ws, size_t ws_size,
                              hipStream_t stream) {
    const float* x     = (const float*)d_in[0];
    const float* Wq    = (const float*)d_in[1];
    const float* b_con = (const float*)d_in[2];
    const float* b_rel = (const float*)d_in[3];
    const float* Wk    = (const float*)d_in[4];
    const float* Wkr   = (const float*)d_in[5];
    const float* Wv    = (const float*)d_in[6];
    const float* bv    = (const float*)d_in[7];
    const int*   xlen  = (const int*)d_in[8];
    float* out = (float*)d_out;

    float* ws = (float*)d_ws;
    float* vmean = ws;                       // 1024 fp32
    ushort_t* ub   = (ushort_t*)(vmean + 1024);
    ushort_t* R3   = ub;                     // 16*2048*320 bf16 = 21 MB
    ushort_t* qcon = R3   + 10485760;
    ushort_t* kbuf = qcon + 2097152;
    ushort_t* vT   = kbuf + 2097152;         // 1024 x 2048 bf16
    ushort_t* qrel = vT   + 2097152;
    ushort_t* xb16 = qrel + 2097152;         // 4096*512 bf16
    ushort_t* krel = xb16 + 2097152;         // 384*512 bf16
    ushort_t* pos  = krel + 196608;          // 384*512 bf16
    ushort_t* WTq  = pos  + 196608;          // 512*512 bf16 each
    ushort_t* WTk  = WTq + 262144;
    ushort_t* WTv  = WTk + 262144;
    ushort_t* WTkr = WTv + 262144;

    prep_kernel<<<dim3(8, 8, 6), 256, 0, stream>>>(x, Wq, Wk, Wv, Wkr,
                                                   WTq, WTk, WTv, WTkr, pos, xb16);
    qkv_gemm<<<dim3(32, 25), 256, 0, stream>>>(xb16, WTq, WTk, WTv, pos, WTkr,
                                               b_con, b_rel, bv, xlen,
                                               qcon, qrel, kbuf, vT, krel);
    rel_gemm<<<dim3(17, 8, 2), 256, 0, stream>>>(qrel, krel, vT, xlen, R3, vmean);
    attn_kernel<<<dim3(32, 8, 2), 256, 0, stream>>>(qcon, kbuf, vT, R3, vmean,
                                                    xlen, out);
}